// Round 8
// baseline (235.579 us; speedup 1.0000x reference)
//
#include <hip/hip_runtime.h>
#include <math.h>

#define BB 8
#define SS 32
#define HN 64
#define TN 512
#define HID 512

typedef __attribute__((ext_vector_type(8))) short short8;
typedef __attribute__((ext_vector_type(4))) float f32x4;

__device__ __forceinline__ float eluf(float x) { return x > 0.f ? x : (expf(x) - 1.f); }

__device__ __forceinline__ short f2bs(float f) {
    union { float f; unsigned int u; } v; v.f = f;
    unsigned int r = v.u + 0x7fffu + ((v.u >> 16) & 1u);
    return (short)(r >> 16);
}
__device__ __forceinline__ float b2f(short s) {
    union { unsigned int u; float f; } v;
    v.u = ((unsigned int)(unsigned short)s) << 16;
    return v.f;
}

__device__ __forceinline__ void gld16(const void* g, void* l) {
    __builtin_amdgcn_global_load_lds(
        (const __attribute__((address_space(1))) void*)g,
        (__attribute__((address_space(3))) void*)l, 16, 0, 0);
}

// ---------------------------------------------------------------------------
// 4-wave GEMM core (R5/R7 structure) for the prep-side GEMMs: C[128x128] =
// act(A@B^T + bias). BK=64. Ls = 16384 shorts. OUTB: 0=f32, 1=bf16.
// ---------------------------------------------------------------------------
template <int ACT, int OUTB>
__device__ __forceinline__ void gcore(
    const short* __restrict__ A, const short* __restrict__ B,
    const float* __restrict__ bias, void* __restrict__ Cv,
    int ldc, int K, int m0, int n0, int cm0, short* Ls)
{
    short* Al = Ls;
    short* Bl = Ls + 8192;
    const int tid  = threadIdx.x;
    const int lane = tid & 63;
    const int w    = tid >> 6;
    const int wr   = w >> 1, wc = w & 1;
    const int l16  = lane & 15, quad = lane >> 4;

    const int srow = w * 16 + (lane >> 2);
    const int scol = (lane & 3) * 8;

    f32x4 acc[4][4];
#pragma unroll
    for (int i = 0; i < 4; ++i)
#pragma unroll
        for (int j = 0; j < 4; ++j) { acc[i][j][0]=0.f; acc[i][j][1]=0.f; acc[i][j][2]=0.f; acc[i][j][3]=0.f; }

    short* lA = Al + w * 512;
    short* lB = Bl + w * 512;
    const long rstep = (long)64 * K;

    const short* Ag = A + (long)(m0 + srow) * K + scol;
    const short* Bg = B + (long)(n0 + srow) * K + scol;
    for (int kt = 0; kt < K; kt += 64) {
        __syncthreads();
        gld16(Ag + kt, lA);
        gld16(Ag + kt + rstep, lA + 2048);
        gld16(Ag + kt + 32, lA + 4096);
        gld16(Ag + kt + 32 + rstep, lA + 4096 + 2048);
        gld16(Bg + kt, lB);
        gld16(Bg + kt + rstep, lB + 2048);
        gld16(Bg + kt + 32, lB + 4096);
        gld16(Bg + kt + 32 + rstep, lB + 4096 + 2048);
        __syncthreads();
#pragma unroll
        for (int h = 0; h < 2; ++h) {
            short8 af[4], bf4[4];
#pragma unroll
            for (int mi = 0; mi < 4; ++mi)
                af[mi] = *(const short8*)(Al + h * 4096 + (wr * 64 + mi * 16 + l16) * 32 + quad * 8);
#pragma unroll
            for (int ni = 0; ni < 4; ++ni)
                bf4[ni] = *(const short8*)(Bl + h * 4096 + (wc * 64 + ni * 16 + l16) * 32 + quad * 8);
#pragma unroll
            for (int mi = 0; mi < 4; ++mi)
#pragma unroll
                for (int ni = 0; ni < 4; ++ni)
                    acc[mi][ni] = __builtin_amdgcn_mfma_f32_16x16x32_bf16(af[mi], bf4[ni], acc[mi][ni], 0, 0, 0);
        }
    }

    __syncthreads();

    float bv[4];
#pragma unroll
    for (int ni = 0; ni < 4; ++ni)
        bv[ni] = bias ? bias[n0 + wc * 64 + ni * 16 + l16] : 0.f;

    if (OUTB == 1) {
        short* eb = Ls + w * 1152;
        const int er = lane >> 2;
        const int ec = (lane & 3) * 16;
#pragma unroll
        for (int mi = 0; mi < 4; ++mi) {
#pragma unroll
            for (int ni = 0; ni < 4; ++ni)
#pragma unroll
                for (int r = 0; r < 4; ++r) {
                    float x = acc[mi][ni][r] + bv[ni];
                    if (ACT == 1) x = eluf(x);
                    eb[(quad * 4 + r) * 72 + ni * 16 + l16] = f2bs(x);
                }
            __builtin_amdgcn_sched_barrier(0);
            short8 v0 = *(const short8*)&eb[er * 72 + ec];
            short8 v1 = *(const short8*)&eb[er * 72 + ec + 8];
            long cb = (long)(cm0 + wr * 64 + mi * 16 + er) * ldc + n0 + wc * 64 + ec;
            *(short8*)((short*)Cv + cb)     = v0;
            *(short8*)((short*)Cv + cb + 8) = v1;
            __builtin_amdgcn_sched_barrier(0);
        }
    } else {
#pragma unroll
        for (int mi = 0; mi < 4; ++mi)
#pragma unroll
            for (int ni = 0; ni < 4; ++ni) {
                int gc = n0 + wc * 64 + ni * 16 + l16;
#pragma unroll
                for (int r = 0; r < 4; ++r) {
                    float x = acc[mi][ni][r] + bv[ni];
                    if (ACT == 1) x = eluf(x);
                    ((float*)Cv)[(long)(cm0 + wr * 64 + mi * 16 + quad * 4 + r) * ldc + gc] = x;
                }
            }
    }
}

// qall (48) | qe (16) | tk (128) in one launch
__global__ __launch_bounds__(256) void mgemm_multi(
    const short* __restrict__ decb, const short* __restrict__ WTall, float* __restrict__ qall,
    const short* __restrict__ embAll, const short* __restrict__ WTe, float* __restrict__ qe,
    const short* __restrict__ WTk, const float* __restrict__ b_tk, short* __restrict__ tkb)
{
    __shared__ short Ls[16384];
    int id = blockIdx.x;
    if (id < 48) {
        int y = id >> 4, x = id & 15;
        gcore<0, 0>(decb, WTall, nullptr, qall, 2048, 512, y * 128, x * 128, y * 128, Ls);
    } else if (id < 64) {
        int id2 = id - 48, y = id2 >> 2, x = id2 & 3;
        gcore<0, 0>(embAll, WTe, nullptr, qe, 512, 512, y * 128, x * 128, y * 128, Ls);
    } else {
        int id3 = id - 64, y = id3 >> 2, x = id3 & 3;
        gcore<1, 1>(embAll, WTk, b_tk, tkb, 512, 512, 512 + y * 128, x * 128, y * 128, Ls);
    }
}

// ---------------------------------------------------------------------------
// prep (vectorized): float4 casts | 2-rows/block float4 gathers | transposes
// ---------------------------------------------------------------------------
struct WTDesc { const float* src[9]; short* dst[9]; };

__global__ __launch_bounds__(256) void prep(
    const float* __restrict__ dec_out, const float* __restrict__ history,
    short* __restrict__ decb,
    const float* __restrict__ emb, const int* __restrict__ head, const int* __restrict__ tail,
    short* __restrict__ embAll, WTDesc wd)
{
    __shared__ float t[32][33];
    const int id = blockIdx.x, tid = threadIdx.x;
    if (id < 132) {
        int i = (id * 256 + tid) * 4;
        float4 v = (i < 131072) ? *(const float4*)(dec_out + i)
                                : *(const float4*)(history + (i - 131072));
        short4 o;
        o.x = f2bs(v.x); o.y = f2bs(v.y); o.z = f2bs(v.z); o.w = f2bs(v.w);
        *(short4*)(decb + i) = o;
    } else if (id < 132 + 2304) {
        int r = (id - 132) * 2 + (tid >> 7);
        int c4 = (tid & 127) * 4;
        int idx = (r < 512) ? head[r] : tail[r - 512];
        float4 v = *(const float4*)(emb + (long)idx * 512 + c4);
        short4 o;
        o.x = f2bs(v.x); o.y = f2bs(v.y); o.z = f2bs(v.z); o.w = f2bs(v.w);
        *(short4*)(embAll + (long)r * 512 + c4) = o;
    } else {
        int q = id - 2436;
        int z = q >> 8, xy = q & 255;
        int x = xy & 15, y = xy >> 4;
        const float* src = wd.src[z];
        short* dst = wd.dst[z];
        int k0 = y * 32, n0 = x * 32;
        int tx = tid & 31, ty = tid >> 5;
#pragma unroll
        for (int i = 0; i < 32; i += 8)
            t[ty + i][tx] = src[(long)(k0 + ty + i) * 512 + n0 + tx];
        __syncthreads();
#pragma unroll
        for (int i = 0; i < 32; i += 8)
            dst[(long)(n0 + ty + i) * 512 + k0 + tx] = f2bs(t[tx][ty + i]);
    }
}

// ---------------------------------------------------------------------------
// L3: build_tq (8192) | tkWT GEMM (128) | hq build (128)
// ---------------------------------------------------------------------------
__global__ __launch_bounds__(256) void l3_kernel(
    const float* __restrict__ qall, const float* __restrict__ qe,
    const float* __restrict__ b_tq, short* __restrict__ tqb,
    const short* __restrict__ WTo1, const short* __restrict__ tkb, short* __restrict__ tkWTb,
    const float* __restrict__ b_hq, float* __restrict__ hqf)
{
    __shared__ short Ls[16384];
    if (blockIdx.x < 8192) {
        long gid = (long)blockIdx.x * 256 + threadIdx.x;
        int r = (int)(gid >> 7), j0 = ((int)gid & 127) * 4;
        int b = r >> 11, rem = r & 2047, s = rem >> 6, h = rem & 63;
        float4 d = *(const float4*)(qall + (long)(b * 32 + s) * 2048 + j0);
        float4 q = *(const float4*)(qall + (long)(256 + b) * 2048 + 1024 + j0);
        float4 e = *(const float4*)(qe + (long)(b * 64 + h) * 512 + j0);
        float4 bb = *(const float4*)(b_tq + j0);
        short4 o;
        o.x = f2bs(eluf(d.x + q.x + e.x + bb.x));
        o.y = f2bs(eluf(d.y + q.y + e.y + bb.y));
        o.z = f2bs(eluf(d.z + q.z + e.z + bb.z));
        o.w = f2bs(eluf(d.w + q.w + e.w + bb.w));
        *(short4*)(tqb + (long)r * 512 + j0) = o;
    } else if (blockIdx.x < 8320) {
        int id2 = blockIdx.x - 8192;
        int z = id2 >> 4, r = id2 & 15;
        int x = r & 3, y = r >> 2;
        gcore<0, 1>(WTo1, tkb + (long)z * 262144, nullptr,
                    tkWTb + (long)z * 262144, 512, 512, y * 128, x * 128, y * 128, Ls);
    } else {
        long gid = (long)(blockIdx.x - 8320) * 256 + threadIdx.x;
        int n = (int)(gid >> 7), j0 = ((int)gid & 127) * 4;
        int b = n >> 5;
        float4 d = *(const float4*)(qall + (long)n * 2048 + 512 + j0);
        float4 h2 = *(const float4*)(qall + (long)(256 + b) * 2048 + 1536 + j0);
        float4 bb = *(const float4*)(b_hq + j0);
        float4 o;
        o.x = eluf(d.x + h2.x + bb.x);
        o.y = eluf(d.y + h2.y + bb.y);
        o.z = eluf(d.z + h2.z + bb.z);
        o.w = eluf(d.w + h2.w + bb.w);
        *(float4*)(hqf + (long)n * 512 + j0) = o;
    }
}

// ---------------------------------------------------------------------------
// 8-wave 64x512 GEMM helper: wave w owns cols [w*64, w*64+64); acc 4x4 f32x4.
// A[64][512] at Ag, B[512][512] (B^T layout) at Bg. BK=32, 16 K-steps.
// ---------------------------------------------------------------------------
__device__ __forceinline__ void gemm8_acc(
    const short* __restrict__ Ag, const short* __restrict__ Bg,
    short* AL, short* BL, f32x4 acc[4][4],
    int w, int lane, int l16, int quad)
{
    const short* ap = Ag + ((w & 3) * 16 + (lane >> 2)) * 512 + (lane & 3) * 8;
    const short* bp = Bg + (long)(w * 64 + (lane >> 2)) * 512 + (lane & 3) * 8;
    for (int kt = 0; kt < 512; kt += 32) {
        __syncthreads();
        if (w < 4) gld16(ap + kt, AL + (w & 3) * 512);
#pragma unroll
        for (int u = 0; u < 4; ++u)
            gld16(bp + (long)u * 16 * 512 + kt, BL + (w * 64 + u * 16) * 32);
        __syncthreads();
        short8 af[4], bf[4];
#pragma unroll
        for (int mi = 0; mi < 4; ++mi)
            af[mi] = *(const short8*)(AL + (mi * 16 + l16) * 32 + quad * 8);
#pragma unroll
        for (int ni = 0; ni < 4; ++ni)
            bf[ni] = *(const short8*)(BL + (w * 64 + ni * 16 + l16) * 32 + quad * 8);
#pragma unroll
        for (int mi = 0; mi < 4; ++mi)
#pragma unroll
            for (int ni = 0; ni < 4; ++ni)
                acc[mi][ni] = __builtin_amdgcn_mfma_f32_16x16x32_bf16(af[mi], bf[ni], acc[mi][ni], 0, 0, 0);
    }
}

// ---------------------------------------------------------------------------
// K4: scores + mask + softmax + P store.  One block per n, 512 threads.
// ---------------------------------------------------------------------------
__global__ __launch_bounds__(512) void k4_scores_sm(
    const short* __restrict__ tqb, const short* __restrict__ tkb,
    const int* __restrict__ adj, const int* __restrict__ dup, short* __restrict__ Pb)
{
    __shared__ short AL[2048];
    __shared__ short BL[16384];
    __shared__ float red[8][64];
    __shared__ float rowv[64];
    const int n = blockIdx.x, b = n >> 5;
    const int tid = threadIdx.x, lane = tid & 63, w = tid >> 6;
    const int l16 = lane & 15, quad = lane >> 4;

    f32x4 acc[4][4];
#pragma unroll
    for (int i = 0; i < 4; ++i)
#pragma unroll
        for (int j = 0; j < 4; ++j) { acc[i][j][0]=0.f; acc[i][j][1]=0.f; acc[i][j][2]=0.f; acc[i][j][3]=0.f; }

    gemm8_acc(tqb + (long)n * 64 * 512, tkb + (long)b * 262144, AL, BL, acc, w, lane, l16, quad);

    // mask: rows of this block are h = 0..63 (s fixed), dup row = n
    const int* adjb = adj + (long)(b * 64) * 512;
    const int* dupb = dup + (long)n * 512;
#pragma unroll
    for (int mi = 0; mi < 4; ++mi)
#pragma unroll
        for (int ni = 0; ni < 4; ++ni) {
            int col = w * 64 + ni * 16 + l16;
            int dv = dupb[col];
#pragma unroll
            for (int r = 0; r < 4; ++r) {
                int row = mi * 16 + quad * 4 + r;
                if (!(adjb[(long)row * 512 + col] && !dv)) acc[mi][ni][r] = -INFINITY;
            }
        }

    // row max: this wave's 64 cols -> cross-wave via LDS
#pragma unroll
    for (int mi = 0; mi < 4; ++mi)
#pragma unroll
        for (int r = 0; r < 4; ++r) {
            float m = fmaxf(fmaxf(acc[mi][0][r], acc[mi][1][r]),
                            fmaxf(acc[mi][2][r], acc[mi][3][r]));
            m = fmaxf(m, __shfl_xor(m, 1));
            m = fmaxf(m, __shfl_xor(m, 2));
            m = fmaxf(m, __shfl_xor(m, 4));
            m = fmaxf(m, __shfl_xor(m, 8));
            if (l16 == 0) red[w][mi * 16 + quad * 4 + r] = m;
        }
    __syncthreads();
    if (tid < 64) {
        float m = red[0][tid];
#pragma unroll
        for (int ww = 1; ww < 8; ++ww) m = fmaxf(m, red[ww][tid]);
        rowv[tid] = m;
    }
    __syncthreads();

    // exp + row sum
#pragma unroll
    for (int mi = 0; mi < 4; ++mi)
#pragma unroll
        for (int r = 0; r < 4; ++r) {
            int row = mi * 16 + quad * 4 + r;
            float m = rowv[row];
            float s = 0.f;
#pragma unroll
            for (int ni = 0; ni < 4; ++ni) {
                float e = (m == -INFINITY) ? 0.f : expf(acc[mi][ni][r] - m);
                acc[mi][ni][r] = e;
                s += e;
            }
            s += __shfl_xor(s, 1);
            s += __shfl_xor(s, 2);
            s += __shfl_xor(s, 4);
            s += __shfl_xor(s, 8);
            if (l16 == 0) red[w][row] = s;
        }
    __syncthreads();
    if (tid < 64) {
        float s = 0.f;
#pragma unroll
        for (int ww = 0; ww < 8; ++ww) s += red[ww][tid];
        rowv[tid] = s > 0.f ? 1.f / s : 0.f;
    }
    __syncthreads();

    // scale -> bf16 -> vectorized store (per-wave LDS staging in BL)
    short* eb = BL + w * 1152;
    const int er = lane >> 2, ec = (lane & 3) * 16;
#pragma unroll
    for (int mi = 0; mi < 4; ++mi) {
#pragma unroll
        for (int ni = 0; ni < 4; ++ni)
#pragma unroll
            for (int r = 0; r < 4; ++r) {
                int row = mi * 16 + quad * 4 + r;
                eb[(quad * 4 + r) * 72 + ni * 16 + l16] = f2bs(acc[mi][ni][r] * rowv[row]);
            }
        __builtin_amdgcn_sched_barrier(0);
        short8 v0 = *(const short8*)&eb[er * 72 + ec];
        short8 v1 = *(const short8*)&eb[er * 72 + ec + 8];
        long cb = ((long)n * 64 + mi * 16 + er) * 512 + w * 64 + ec;
        *(short8*)(Pb + cb)     = v0;
        *(short8*)(Pb + cb + 8) = v1;
        __builtin_amdgcn_sched_barrier(0);
    }
}

// ---------------------------------------------------------------------------
// K5: gh (dual GEMM) -> tanh -> LDS -> hk GEMM -> hs -> head softmax -> prob.
// One block per n, 512 threads.
// ---------------------------------------------------------------------------
__global__ __launch_bounds__(512) void k5_ghmega(
    const short* __restrict__ Pb, const short* __restrict__ tqb,
    const short* __restrict__ tkWTb, const short* __restrict__ WTo2,
    const short* __restrict__ WThk, const float* __restrict__ b_hk,
    const float* __restrict__ hqf, const int* __restrict__ head,
    float* __restrict__ out)
{
    __shared__ short AL[2048];
    __shared__ short BL[16384];
    __shared__ short GH[64 * 520];
    __shared__ float red[8][64];
    __shared__ float hal[64];
    const int n = blockIdx.x, b = n >> 5;
    const int tid = threadIdx.x, lane = tid & 63, w = tid >> 6;
    const int l16 = lane & 15, quad = lane >> 4;

    f32x4 acc[4][4];
#pragma unroll
    for (int i = 0; i < 4; ++i)
#pragma unroll
        for (int j = 0; j < 4; ++j) { acc[i][j][0]=0.f; acc[i][j][1]=0.f; acc[i][j][2]=0.f; acc[i][j][3]=0.f; }

    // gh_pre = P @ tkWT[b]^T + tq @ Wtout2^T
    gemm8_acc(Pb + (long)n * 64 * 512, tkWTb + (long)b * 262144, AL, BL, acc, w, lane, l16, quad);
    gemm8_acc(tqb + (long)n * 64 * 512, WTo2, AL, BL, acc, w, lane, l16, quad);

    // tanh -> GH (bf16, padded stride 520 for bank spread)
#pragma unroll
    for (int mi = 0; mi < 4; ++mi)
#pragma unroll
        for (int ni = 0; ni < 4; ++ni)
#pragma unroll
            for (int r = 0; r < 4; ++r)
                GH[(mi * 16 + quad * 4 + r) * 520 + w * 64 + ni * 16 + l16] =
                    f2bs(tanhf(acc[mi][ni][r]));
    __syncthreads();

    // hk = elu(GH @ Whk^T + b_hk): A from LDS, B staged
#pragma unroll
    for (int i = 0; i < 4; ++i)
#pragma unroll
        for (int j = 0; j < 4; ++j) { acc[i][j][0]=0.f; acc[i][j][1]=0.f; acc[i][j][2]=0.f; acc[i][j][3]=0.f; }
    {
        const short* bp = WThk + (long)(w * 64 + (lane >> 2)) * 512 + (lane & 3) * 8;
        for (int kt = 0; kt < 512; kt += 32) {
            __syncthreads();
#pragma unroll
            for (int u = 0; u < 4; ++u)
                gld16(bp + (long)u * 16 * 512 + kt, BL + (w * 64 + u * 16) * 32);
            __syncthreads();
            short8 af[4], bf[4];
#pragma unroll
            for (int mi = 0; mi < 4; ++mi)
                af[mi] = *(const short8*)(GH + (mi * 16 + l16) * 520 + kt + quad * 8);
#pragma unroll
            for (int ni = 0; ni < 4; ++ni)
                bf[ni] = *(const short8*)(BL + (w * 64 + ni * 16 + l16) * 32 + quad * 8);
#pragma unroll
            for (int mi = 0; mi < 4; ++mi)
#pragma unroll
                for (int ni = 0; ni < 4; ++ni)
                    acc[mi][ni] = __builtin_amdgcn_mfma_f32_16x16x32_bf16(af[mi], bf[ni], acc[mi][ni], 0, 0, 0);
        }
    }

    // hs[row] = sum_col elu(hk + b_hk) * hq[n][col]
    float bv[4], hqv[4];
#pragma unroll
    for (int ni = 0; ni < 4; ++ni) {
        int col = w * 64 + ni * 16 + l16;
        bv[ni]  = b_hk[col];
        hqv[ni] = hqf[(long)n * 512 + col];
    }
#pragma unroll
    for (int mi = 0; mi < 4; ++mi)
#pragma unroll
        for (int r = 0; r < 4; ++r) {
            float p = 0.f;
#pragma unroll
            for (int ni = 0; ni < 4; ++ni)
                p += eluf(acc[mi][ni][r] + bv[ni]) * hqv[ni];
            p += __shfl_xor(p, 1);
            p += __shfl_xor(p, 2);
            p += __shfl_xor(p, 4);
            p += __shfl_xor(p, 8);
            if (l16 == 0) red[w][mi * 16 + quad * 4 + r] = p;
        }
    __syncthreads();

    // head softmax with length mask (wave 0)
    if (tid < 64) {
        float sv = red[0][tid] + red[1][tid] + red[2][tid] + red[3][tid]
                 + red[4][tid] + red[5][tid] + red[6][tid] + red[7][tid];
        int hv = head[b * 64 + tid];
        unsigned long long ball = __ballot(hv != 0);
        int len = __popcll(ball);
        sv = (tid < len) ? sv : -INFINITY;
        float m = sv;
#pragma unroll
        for (int d = 32; d >= 1; d >>= 1) m = fmaxf(m, __shfl_xor(m, d));
        float e = expf(sv - m);
        float sum = e;
#pragma unroll
        for (int d = 32; d >= 1; d >>= 1) sum += __shfl_xor(sum, d);
        hal[tid] = e / sum;
    }
    __syncthreads();

    // prob: wave w covers k = w*8..w*8+8; lane owns 8 t's; partials in BL (f32)
    float* part = (float*)BL;
    {
        float pacc[8] = {};
        const short* prow = Pb + ((long)n * 64 + w * 8) * 512 + lane * 8;
#pragma unroll
        for (int kk = 0; kk < 8; ++kk) {
            float a = hal[w * 8 + kk];
            short8 tv = *(const short8*)(prow + (long)kk * 512);
#pragma unroll
            for (int u = 0; u < 8; ++u) pacc[u] += a * b2f(tv[u]);
        }
        float4* pp = (float4*)&part[w * 512 + lane * 8];
        pp[0] = make_float4(pacc[0], pacc[1], pacc[2], pacc[3]);
        pp[1] = make_float4(pacc[4], pacc[5], pacc[6], pacc[7]);
    }
    __syncthreads();
    {
        float a = 0.f;
#pragma unroll
        for (int ww = 0; ww < 8; ++ww) a += part[ww * 512 + tid];
        out[(long)n * 512 + tid] = logf(a + 1e-20f);
    }
}

extern "C" void kernel_launch(void* const* d_in, const int* in_sizes, int n_in,
                              void* d_out, int out_size, void* d_ws, size_t ws_size,
                              hipStream_t stream)
{
    const float* dec_out = (const float*)d_in[0];
    const float* history = (const float*)d_in[1];
    const int*   head    = (const int*)d_in[2];
    const int*   tail    = (const int*)d_in[3];
    const int*   adj     = (const int*)d_in[4];
    const int*   dup     = (const int*)d_in[5];
    const float* emb     = (const float*)d_in[6];
    const float* W_tq    = (const float*)d_in[7];
    const float* b_tq    = (const float*)d_in[8];
    const float* W_tk    = (const float*)d_in[9];
    const float* b_tk    = (const float*)d_in[10];
    const float* W_tout  = (const float*)d_in[11];
    const float* W_hq    = (const float*)d_in[12];
    const float* b_hq    = (const float*)d_in[13];
    const float* W_hk    = (const float*)d_in[14];
    const float* b_hk    = (const float*)d_in[15];
    float* out = (float*)d_out;

    char* ws = (char*)d_ws;
    auto alloc = [&](size_t bytes) -> void* {
        char* p = ws;
        ws += (bytes + 255) & ~(size_t)255;
        return (void*)p;
    };
    short* decb   = (short*)alloc((size_t)384 * 512 * 2);    // dec 0..255, hist 256..263
    short* embAll = (short*)alloc((size_t)4608 * 512 * 2);   // head 0..511, tail 512..4607
    short* WT     = (short*)alloc((size_t)9 * 512 * 512 * 2);
    float* qall   = (float*)alloc((size_t)384 * 2048 * 4);   // [qd|hqp|qh'|hq2']
    float* qe     = (float*)alloc((size_t)512 * 512 * 4);
    float* hqf    = (float*)alloc((size_t)256 * 512 * 4);
    short* tkb    = (short*)alloc((size_t)4096 * 512 * 2);
    short* tkWTb  = (short*)alloc((size_t)4096 * 512 * 2);
    short* tqb    = (short*)alloc((size_t)16384 * 512 * 2);
    short* Pb     = (short*)alloc((size_t)16384 * 512 * 2);  // tail_attn

    // WT slab: 0 Wd^T | 1 Whq1^T | 2 Wtq2^T | 3 Whq2^T | 4 We^T | 5 Wtk^T
    //          6 Wtout1^T | 7 Wtout2^T | 8 Whk^T
    WTDesc wd;
    wd.src[0] = W_tq;               wd.dst[0] = WT;
    wd.src[1] = W_hq;               wd.dst[1] = WT + (size_t)1 * 262144;
    wd.src[2] = W_tq + 512 * 512;   wd.dst[2] = WT + (size_t)2 * 262144;
    wd.src[3] = W_hq + 512 * 512;   wd.dst[3] = WT + (size_t)3 * 262144;
    wd.src[4] = W_tq + 1024 * 512;  wd.dst[4] = WT + (size_t)4 * 262144;
    wd.src[5] = W_tk;               wd.dst[5] = WT + (size_t)5 * 262144;
    wd.src[6] = W_tout;             wd.dst[6] = WT + (size_t)6 * 262144;
    wd.src[7] = W_tout + 512 * 512; wd.dst[7] = WT + (size_t)7 * 262144;
    wd.src[8] = W_hk;               wd.dst[8] = WT + (size_t)8 * 262144;

    // 1: casts / gathers / weight transposes
    prep<<<4740, 256, 0, stream>>>(dec_out, history, decb, emb, head, tail, embAll, wd);
    // 2: qall | qe | tk
    mgemm_multi<<<192, 256, 0, stream>>>(decb, WT, qall, embAll, WT + (size_t)4 * 262144, qe,
                                         WT + (size_t)5 * 262144, b_tk, tkb);
    // 3: build tq | tkWT = Wtout1^T @ tk^T (per b) | build hq
    l3_kernel<<<8448, 256, 0, stream>>>(qall, qe, b_tq, tqb, WT + (size_t)6 * 262144, tkb, tkWTb,
                                        b_hq, hqf);
    // 4: scores + mask + softmax -> P   (one block per n)
    k4_scores_sm<<<256, 512, 0, stream>>>(tqb, tkb, adj, dup, Pb);
    // 5: gh -> hk -> hs -> head softmax -> prob -> log   (one block per n)
    k5_ghmega<<<256, 512, 0, stream>>>(Pb, tqb, tkWTb, WT + (size_t)7 * 262144,
                                       WT + (size_t)8 * 262144, b_hk, hqf, head, out);
}